// Round 4
// baseline (468.748 us; speedup 1.0000x reference)
//
#include <hip/hip_runtime.h>
#include <hip/hip_bf16.h>

#define NQ 10000
#define BS 6
#define NV 30825   // 23200 + 5800 + 1450 + 375

// Per-level geometry. vproj layout per batch (64B units of [head-row of 32ch]):
//   level l: unit = ubase[l] + (y*8 + h)*W + x   (x-adjacent => contiguous!)
//   ubase: 0, 185600, 232000, 243600 ; per-batch 246600 units (15,782,400 B)

typedef __attribute__((ext_vector_type(8))) short bf16x8;
typedef __attribute__((ext_vector_type(8))) unsigned short u16x8;
typedef __attribute__((ext_vector_type(4))) float f32x4;
typedef __attribute__((ext_vector_type(2))) float f32x2;

__device__ __forceinline__ void gload_lds16(const void* g, void* l) {
  __builtin_amdgcn_global_load_lds(
      (const __attribute__((address_space(1))) unsigned int*)g,
      (__attribute__((address_space(3))) unsigned int*)l, 16, 0, 0);
}

__device__ __forceinline__ unsigned short bf_bits(float f) {
  __hip_bfloat16 h = __float2bfloat16(f);
  return *(unsigned short*)&h;
}

// ---------------------------------------------------------------------------
// Pack + transpose weights to bf16.
// ---------------------------------------------------------------------------
__global__ __launch_bounds__(256) void prep_weights_kernel(
    const float* __restrict__ w_val, const float* __restrict__ w_off,
    const float* __restrict__ w_attn, const float* __restrict__ b_off,
    const float* __restrict__ b_attn, unsigned short* __restrict__ wvalT,
    unsigned short* __restrict__ wpackT, float* __restrict__ bpack) {
  int i = blockIdx.x * 256 + threadIdx.x;
  if (i < 65536) {
    int n = i >> 8, k = i & 255;
    wvalT[i] = bf_bits(w_val[k * 256 + n]);
  } else if (i < 65536 + 196608) {
    int j = i - 65536;
    int n = j >> 8, k = j & 255;
    float v = (n < 512) ? w_off[k * 512 + n] : w_attn[k * 256 + (n - 512)];
    wpackT[j] = bf_bits(v);
  } else if (i < 65536 + 196608 + 768) {
    int j = i - 262144;
    bpack[j] = (j < 512) ? b_off[j] : b_attn[j - 512];
  }
}

// ---------------------------------------------------------------------------
// MFMA GEMM with fused A conversion:
//   C[M,N](bf16) = bf16(A[M,256] f32) @ WT[N,256]^T(bf16) + bias[N](f32)
// 128x128 tile, BK=64, 4 waves (2x2 of 64x64).
// SCATTER=false: linear C [M][N].
// SCATTER=true : value-projection scatter into the level-blocked vproj layout.
// ---------------------------------------------------------------------------
template <bool SCATTER>
__global__ __launch_bounds__(256) void gemm_mfma_kernel(
    const float* __restrict__ A, const unsigned short* __restrict__ WT,
    const float* __restrict__ bias, unsigned short* __restrict__ C, int M, int N) {
  __shared__ short As[128 * 64];  // [row][k] bf16, 128B rows
  __shared__ short Bs[128 * 64];  // [col][k] bf16, 128B rows (WT layout)
  const int tid = threadIdx.x;
  const int wv = tid >> 6;
  const int lane = tid & 63;
  const int wr = wv >> 1, wc = wv & 1;
  const int m0 = blockIdx.x * 128;
  const int n0 = blockIdx.y * 128;

  f32x4 acc[4][4] = {};

  for (int kt = 0; kt < 4; ++kt) {
#pragma unroll
    for (int j = 0; j < 4; ++j) {
      int u = j * 256 + tid;
      int row = u >> 3;
      int kbyte = (u & 7) * 16;
      int ldsoff = (j * 256 + wv * 64) * 16;  // wave-uniform base (bytes)
      gload_lds16((const char*)WT + (size_t)(n0 + row) * 512 + kt * 128 + kbyte,
                  (char*)Bs + ldsoff);
    }
#pragma unroll
    for (int j = 0; j < 4; ++j) {
      int u = j * 256 + tid;
      int row = u >> 3, oct = u & 7;
      int gr = m0 + row; if (gr >= M) gr = M - 1;
      const float4* ap = (const float4*)(A + (size_t)gr * 256 + kt * 64 + oct * 8);
      float4 a0 = ap[0], a1 = ap[1];
      u16x8 pk = { bf_bits(a0.x), bf_bits(a0.y), bf_bits(a0.z), bf_bits(a0.w),
                   bf_bits(a1.x), bf_bits(a1.y), bf_bits(a1.z), bf_bits(a1.w) };
      *(u16x8*)&As[row * 64 + oct * 8] = pk;
    }
    __syncthreads();
#pragma unroll
    for (int kk = 0; kk < 2; ++kk) {
      bf16x8 af[4], bfr[4];
#pragma unroll
      for (int mi = 0; mi < 4; ++mi) {
        int off = (wr * 64 + mi * 16 + (lane & 15)) * 64 + kk * 32 + (lane >> 4) * 8;
        af[mi] = *(const bf16x8*)&As[off];
      }
#pragma unroll
      for (int ni = 0; ni < 4; ++ni) {
        int off = (wc * 64 + ni * 16 + (lane & 15)) * 64 + kk * 32 + (lane >> 4) * 8;
        bfr[ni] = *(const bf16x8*)&Bs[off];
      }
#pragma unroll
      for (int mi = 0; mi < 4; ++mi)
#pragma unroll
        for (int ni = 0; ni < 4; ++ni)
          acc[mi][ni] = __builtin_amdgcn_mfma_f32_16x16x32_bf16(
              af[mi], bfr[ni], acc[mi][ni], 0, 0, 0);
    }
    __syncthreads();
  }

  const int colb = n0 + wc * 64 + (lane & 15);
  float bvn[4];
#pragma unroll
  for (int ni = 0; ni < 4; ++ni) bvn[ni] = bias[colb + ni * 16];
#pragma unroll
  for (int mi = 0; mi < 4; ++mi) {
#pragma unroll
    for (int r = 0; r < 4; ++r) {
      int row = m0 + wr * 64 + mi * 16 + (lane >> 4) * 4 + r;
      if (row >= M) continue;
      if (!SCATTER) {
#pragma unroll
        for (int ni = 0; ni < 4; ++ni)
          C[(size_t)row * N + colb + ni * 16] = bf_bits(acc[mi][ni][r] + bvn[ni]);
      } else {
        int b = row / NV;
        int pix = row - b * NV;
        int ubase, Wl, y, x;
        if (pix < 23200)      { int pl = pix;         y = pl / 200; x = pl - y * 200; ubase = 0;      Wl = 200; }
        else if (pix < 29000) { int pl = pix - 23200; y = pl / 100; x = pl - y * 100; ubase = 185600; Wl = 100; }
        else if (pix < 30450) { int pl = pix - 29000; y = pl / 50;  x = pl - y * 50;  ubase = 232000; Wl = 50;  }
        else                  { int pl = pix - 30450; y = pl / 25;  x = pl - y * 25;  ubase = 243600; Wl = 25;  }
        size_t bu = (size_t)b * 246600 + ubase + (size_t)(y * 8) * Wl + x;
#pragma unroll
        for (int ni = 0; ni < 4; ++ni) {
          int col = colb + ni * 16;
          int h = col >> 5, ch = col & 31;
          C[(bu + (size_t)h * Wl) * 32 + ch] = bf_bits(acc[mi][ni][r] + bvn[ni]);
        }
      }
    }
  }
}

// ---------------------------------------------------------------------------
// Sampling kernel:
//  phase 1: 256 threads = 256 (h,l,p) samples; softmax + bilinear setup.
//           Per sample, 2 y-rows; each row's x0/x1 corner PAIR is one
//           contiguous 128B segment in the new vproj layout. Store pair
//           unit-index + (wA,wB) column weights.
//  phase 2: 8-lane groups cooperatively gather 128B pair segments
//           (8 lanes x 16B); lane's column-half picks wA/wB. 16 gathers/lane.
// ---------------------------------------------------------------------------
__global__ __launch_bounds__(256) void msda_sample_kernel(
    const __hip_bfloat16* __restrict__ vproj,  // level-blocked layout (see top)
    const __hip_bfloat16* __restrict__ C2,     // [BS*NQ, 768]: 512 off | 256 attn
    const float* __restrict__ ref,             // [BS*NQ, 4, 2]
    float* __restrict__ out) {                 // [BS*NQ, 256]
  const int bq = blockIdx.x;
  const int b = bq / NQ;
  const int tid = threadIdx.x;

  __shared__ int    s_pidx[512];
  __shared__ float2 s_w2[512];

  {  // ---- phase 1 : one sample per thread ----
    const int h = tid >> 5;
    const int lp = tid & 31;
    const int l = lp >> 3, p = lp & 7, z = p & 3;
    const __hip_bfloat162* offp = (const __hip_bfloat162*)(C2 + (size_t)bq * 768);
    __hip_bfloat162 ob = offp[tid];
    float ox = __bfloat162float(ob.x), oy = __bfloat162float(ob.y);
    float logit = __bfloat162float(C2[(size_t)bq * 768 + 512 + tid]);

    float mx = logit;
#pragma unroll
    for (int m = 16; m >= 1; m >>= 1) mx = fmaxf(mx, __shfl_xor(mx, m, 32));
    float e = __expf(logit - mx);
    float s = e;
#pragma unroll
    for (int m = 16; m >= 1; m >>= 1) s += __shfl_xor(s, m, 32);
    float aw = e / s;

    float2 rz = *(const float2*)(ref + (size_t)bq * 8 + z * 2);
    const int W = (l == 0) ? 200 : (l == 1) ? 100 : (l == 2) ? 50 : 25;
    const int H = (l == 0) ? 116 : (l == 1) ? 58 : (l == 2) ? 29 : 15;
    const int ub = (l == 0) ? 0 : (l == 1) ? 185600 : (l == 2) ? 232000 : 243600;

    float x = rz.x * (float)W + ox - 0.5f;
    float y = rz.y * (float)H + oy - 0.5f;
    float x0f = floorf(x), y0f = floorf(y);
    float lx = x - x0f, ly = y - y0f;
    int x0 = (int)x0f, y0 = (int)y0f;
    int x1 = x0 + 1, y1 = y0 + 1;

    float wx0 = 1.f - lx, wx1 = lx;
    if (!((x0 >= 0) & (x0 < W))) wx0 = 0.f;
    if (!((x1 >= 0) & (x1 < W))) wx1 = 0.f;
    float wy0 = (1.f - ly) * aw, wy1 = ly * aw;
    if (!((y0 >= 0) & (y0 < H))) wy0 = 0.f;
    if (!((y1 >= 0) & (y1 < H))) wy1 = 0.f;

    int px  = min(max(x0, 0), W - 2);
    int x0c = min(max(x0, 0), W - 1);
    int x1c = min(max(x1, 0), W - 1);
    // distribute corner weights onto the pair's two columns (px, px+1)
    float wA = (x0c == px     ? wx0 : 0.f) + (x1c == px     ? wx1 : 0.f);
    float wB = (x0c == px + 1 ? wx0 : 0.f) + (x1c == px + 1 ? wx1 : 0.f);
    int y0c = min(max(y0, 0), H - 1);
    int y1c = min(max(y1, 0), H - 1);

    const int g = h * 4 + l;
    const int t0 = (p * 2 + 0) * 32 + g;
    s_pidx[t0]      = ub + (y0c * 8 + h) * W + px;
    s_w2[t0]        = make_float2(wy0 * wA, wy0 * wB);
    s_pidx[t0 + 32] = ub + (y1c * 8 + h) * W + px;
    s_w2[t0 + 32]   = make_float2(wy1 * wA, wy1 * wB);
  }
  __syncthreads();

  // ---- phase 2 : cooperative 128B pair gathers ----
  const int g = tid >> 3;          // 32 groups: g = h*4 + sub
  const int lane8 = tid & 7;       // colhalf*4 + e
  const int colhalf = lane8 >> 2;
  const char* vbb = (const char*)vproj + (size_t)b * 15782400 + lane8 * 16;

  f32x2 acc0 = {0.f, 0.f}, acc1 = {0.f, 0.f}, acc2 = {0.f, 0.f}, acc3 = {0.f, 0.f};
#pragma unroll
  for (int t = 0; t < 16; ++t) {
    int idx = t * 32 + g;
    int pidx = s_pidx[idx];
    float2 w2 = s_w2[idx];
    float w = colhalf ? w2.y : w2.x;
    uint4 v = *(const uint4*)(vbb + ((size_t)(unsigned)pidx << 6));
    f32x2 wv = {w, w};
    f32x2 p0 = {__uint_as_float(v.x << 16), __uint_as_float(v.x & 0xffff0000u)};
    f32x2 p1 = {__uint_as_float(v.y << 16), __uint_as_float(v.y & 0xffff0000u)};
    f32x2 p2 = {__uint_as_float(v.z << 16), __uint_as_float(v.z & 0xffff0000u)};
    f32x2 p3 = {__uint_as_float(v.w << 16), __uint_as_float(v.w & 0xffff0000u)};
    acc0 += wv * p0;
    acc1 += wv * p1;
    acc2 += wv * p2;
    acc3 += wv * p3;
  }

  // reduce over colhalf (mask 4) and sub (masks 8, 16) within 32-lane group
#pragma unroll
  for (int m = 4; m <= 16; m <<= 1) {
    acc0.x += __shfl_xor(acc0.x, m, 32);  acc0.y += __shfl_xor(acc0.y, m, 32);
    acc1.x += __shfl_xor(acc1.x, m, 32);  acc1.y += __shfl_xor(acc1.y, m, 32);
    acc2.x += __shfl_xor(acc2.x, m, 32);  acc2.y += __shfl_xor(acc2.y, m, 32);
    acc3.x += __shfl_xor(acc3.x, m, 32);  acc3.y += __shfl_xor(acc3.y, m, 32);
  }

  if ((tid & 31) < 4) {
    const int h = tid >> 5;
    const int e = tid & 3;
    float4* op = (float4*)(out + (size_t)bq * 256 + h * 32 + e * 8);
    op[0] = make_float4(acc0.x, acc0.y, acc1.x, acc1.y);
    op[1] = make_float4(acc2.x, acc2.y, acc3.x, acc3.y);
  }
}

extern "C" void kernel_launch(void* const* d_in, const int* in_sizes, int n_in,
                              void* d_out, int out_size, void* d_ws, size_t ws_size,
                              hipStream_t stream) {
  const float* query  = (const float*)d_in[0];
  const float* value  = (const float*)d_in[1];
  const float* refp   = (const float*)d_in[2];
  const float* w_off  = (const float*)d_in[3];
  const float* b_off  = (const float*)d_in[4];
  const float* w_attn = (const float*)d_in[5];
  const float* b_attn = (const float*)d_in[6];
  const float* w_val  = (const float*)d_in[7];
  const float* b_val  = (const float*)d_in[8];
  float* out = (float*)d_out;

  char* ws = (char*)d_ws;
  // layout (bytes):
  //   vproj  bf16 level-blocked  @ 0           (94,694,400)
  //   C2     bf16 [60000*768]    @ 94,694,400  (92,160,000)
  //   wvalT  bf16 [256*256]      @ 186,854,400 (131,072)
  //   wpackT bf16 [768*256]      @ 186,985,472 (393,216)
  //   bpack  f32  [768]          @ 187,378,688 (3,072)
  unsigned short* vproj  = (unsigned short*)(ws);
  unsigned short* C2     = (unsigned short*)(ws + 94694400);
  unsigned short* wvalT  = (unsigned short*)(ws + 186854400);
  unsigned short* wpackT = (unsigned short*)(ws + 186985472);
  float*          bpack  = (float*)        (ws + 187378688);

  const int Mv = BS * NV;  // 184950
  const int Mq = BS * NQ;  // 60000

  prep_weights_kernel<<<1032, 256, 0, stream>>>(w_val, w_off, w_attn, b_off, b_attn,
                                                wvalT, wpackT, bpack);
  gemm_mfma_kernel<true><<<dim3((Mv + 127) / 128, 2), 256, 0, stream>>>(
      value, wvalT, b_val, vproj, Mv, 256);
  gemm_mfma_kernel<false><<<dim3((Mq + 127) / 128, 6), 256, 0, stream>>>(
      query, wpackT, bpack, C2, Mq, 768);
  msda_sample_kernel<<<BS * NQ, 256, 0, stream>>>(
      (const __hip_bfloat16*)vproj, (const __hip_bfloat16*)C2, refp, out);
}